// Round 12
// baseline (36.238 us; speedup 1.0000x reference)
//
#include <hip/hip_runtime.h>
#include <math.h>

#define BB 2
#define NN 4096
#define CC 33
#define TILE 64
#define NTILES (NN / TILE)            // 64
#define NPB 1056                      // 64x128 blocks per batch = sum over ti of (32 - ti/2)
#define PAIRBLK (BB * NPB)            // 2112 = 33 per slot x 64 slots
#define NDIAG (BB * NTILES)           // 128 diagonal blocks own CE/focal/match
#define NSLOT 64
#define SLOTSTR 32                    // 128 B between slots (distinct L2 lines)

typedef __attribute__((ext_vector_type(8))) short frag_ab;   // 8 bf16 (4 VGPRs)
typedef __attribute__((ext_vector_type(4))) float f32x4;     // 4 fp32 accum

__device__ __forceinline__ float fast_sqrt(float x) {
    return __builtin_amdgcn_sqrtf(x);                        // v_sqrt_f32, ~2 ULP
}
__device__ __forceinline__ unsigned f2bf(float x) {          // RNE, x >= 0 finite
    unsigned u = __float_as_uint(x);
    return (u + 0x7FFFu + ((u >> 16) & 1u)) >> 16;
}
__device__ __forceinline__ float bf2f(unsigned b) {
    return __uint_as_float(b << 16);
}

// ONE kernel. Per block: flat-stage raw f32 tile rows -> LDS; wave-parallel
// in-register softmax (thread (col,kc) owns classes kc*8..+7 of its row = the
// exact MFMA fragment layout; row max/sum via shfl_xor over the row's 4
// lanes); bf16 MFMA Gram + distance epilogue; R8 two-level slot completion
// protocol (agent atomics, vmcnt(0), no fences); winner block finalizes.
__global__ __launch_bounds__(256) void fused_kernel(
    const float* __restrict__ pred, const int* __restrict__ targets,
    const int* __restrict__ pred_choice,
    float* __restrict__ slotf, unsigned* __restrict__ subcnt,
    unsigned* __restrict__ master,
    float* __restrict__ part_ce, float* __restrict__ part_fo,
    int* __restrict__ part_mt, float* __restrict__ out)
{
    __shared__ __align__(16) float sraw[192 * CC];    // 25.3 KB raw f32 rows
    __shared__ float red[4], redc[4], redf[4];
    __shared__ int redm[4];
    __shared__ int lastFlag;
    __shared__ double lds_ce[4], lds_fo[4], lds_pr[4];
    __shared__ int lds_mt[4];

    int bid = blockIdx.x;
    int b = bid / NPB;
    int t = bid % NPB;

    // closed-form decode (proven R11): row-pair p has (32-p) blocks each for
    // ti=2p,2p+1; cum(p) = p*(65-p).
    int p = (int)(32.5f - fast_sqrt(fmaxf(1056.25f - (float)t, 0.0f)));
    if (p < 0) p = 0;
    if (p > 31) p = 31;
    while (p > 0 && p * (65 - p) > t) --p;
    while (p < 31 && (p + 1) * (64 - p) <= t) ++p;
    int rem = t - p * (65 - p);
    int c0 = 32 - p;
    int ti = 2 * p + (rem >= c0);
    int u = (rem >= c0) ? rem - c0 : rem;
    int tjA = ti + 2 * u;
    bool hasB = (tjA + 1 < NTILES);
    bool diagA = (tjA == ti);
    int i0 = ti * TILE, j0A = tjA * TILE;

    // ---- phase 1: flat coalesced staging of raw f32 rows (both chunks
    //      contiguous & 16B-aligned: row base = 64-multiple * 132 B)
    {
        const float4* srcI = (const float4*)(pred + ((size_t)b * NN + i0) * CC);
        const float4* srcJ = (const float4*)(pred + ((size_t)b * NN + j0A) * CC);
        float4* dI = (float4*)sraw;
        float4* dJ = (float4*)(sraw + 64 * CC);
        int jf4 = hasB ? 1056 : 528;                  // 128 or 64 rows * 33/4
        for (int k = threadIdx.x; k < 528; k += 256) dI[k] = srcI[k];
        for (int k = threadIdx.x; k < jf4; k += 256) dJ[k] = srcJ[k];
    }
    __syncthreads();

    int l = threadIdx.x & 63;
    int w = threadIdx.x >> 6;          // wave = 16-row strip of the i-tile
    int col = l & 15;
    int kc = l >> 4;                   // k-chunk: classes kc*8 .. kc*8+7

    // ---- A-row softmax in registers (row = local 16w+col; 4 lanes collab)
    float ea[8], sqA, c32A, invA, e32A;
    {
        int rbase = (16 * w + col) * CC;
        #pragma unroll
        for (int c = 0; c < 8; c++) ea[c] = sraw[rbase + kc * 8 + c];
        float v32 = sraw[rbase + 32];
        float m = ea[0];
        #pragma unroll
        for (int c = 1; c < 8; c++) m = fmaxf(m, ea[c]);
        m = fmaxf(m, __shfl_xor(m, 16));
        m = fmaxf(m, __shfl_xor(m, 32));
        m = fmaxf(m, v32);
        float s = 0.0f;
        #pragma unroll
        for (int c = 0; c < 8; c++) { ea[c] = __expf(ea[c] - m); s += ea[c]; }
        e32A = __expf(v32 - m);
        s += __shfl_xor(s, 16);
        s += __shfl_xor(s, 32);
        s += e32A;
        invA = 1.0f / s;
        float sq = 0.0f;
        #pragma unroll
        for (int c = 0; c < 8; c++) {
            float pf = bf2f(f2bf(ea[c] * invA));
            sq += pf * pf;
        }
        sq += __shfl_xor(sq, 16);
        sq += __shfl_xor(sq, 32);
        c32A = bf2f(f2bf(e32A * invA));
        sqA = sq + c32A * c32A;
    }

    // pack A fragment (rounded bf16 probs, classes kc*8..+7)
    frag_ab afr;
    {
        union { unsigned u4[4]; frag_ab f; } cvt;
        #pragma unroll
        for (int k = 0; k < 4; k++)
            cvt.u4[k] = f2bf(ea[2 * k] * invA) | (f2bf(ea[2 * k + 1] * invA) << 16);
        afr = cvt.f;
    }

    // ---- CE/focal/match once per row (diagonal blocks, kc==0 lanes count)
    float ce = 0.0f, fo = 0.0f; int mt = 0;
    if (diagA) {
        int ga = b * NN + i0 + 16 * w + col;
        int tg = targets[ga];
        float cand = 0.0f;
        #pragma unroll
        for (int c = 0; c < 8; c++)
            cand = ((tg >> 3) == kc && (tg & 7) == c) ? ea[c] : cand;
        if (tg == 32 && kc == 0) cand = e32A;
        cand += __shfl_xor(cand, 16);
        cand += __shfl_xor(cand, 32);
        float pt = cand * invA;                       // raw-space softmax prob
        if (kc == 0) {
            ce = -__logf(pt);
            float om = 1.0f - pt;
            fo = om * om;
            mt = (tg == pred_choice[ga]) ? 1 : 0;
        }
    }

    // ---- gather C-layout row metadata: rows 16w + kc*4 + r
    float qi[4], c32a[4];
    #pragma unroll
    for (int r = 0; r < 4; r++) {
        int src = (kc * 4 + r) + (l & 48);            // same kc-group lane of that row
        qi[r]   = __shfl(sqA, src);
        c32a[r] = __shfl(c32A, src);
    }
    int gi0 = i0 + 16 * w + kc * 4;

    // ---- MFMA Gram + distance epilogue over two j-tiles
    float ssum = 0.0f;
    for (int jt = 0; jt < 2; jt++) {
        if (jt == 1 && !hasB) break;                  // block-uniform
        int j0 = j0A + jt * TILE;
        bool dg = (jt == 0) && diagA;

        #pragma unroll
        for (int n = 0; n < 4; n++) {
            // B-row softmax (row local 64 + jt*64 + 16n + col; same 4-lane collab)
            int rbase = (64 + jt * 64 + 16 * n + col) * CC;
            float eb[8];
            #pragma unroll
            for (int c = 0; c < 8; c++) eb[c] = sraw[rbase + kc * 8 + c];
            float v32 = sraw[rbase + 32];
            float m = eb[0];
            #pragma unroll
            for (int c = 1; c < 8; c++) m = fmaxf(m, eb[c]);
            m = fmaxf(m, __shfl_xor(m, 16));
            m = fmaxf(m, __shfl_xor(m, 32));
            m = fmaxf(m, v32);
            float s = 0.0f;
            #pragma unroll
            for (int c = 0; c < 8; c++) { eb[c] = __expf(eb[c] - m); s += eb[c]; }
            float e32 = __expf(v32 - m);
            s += __shfl_xor(s, 16);
            s += __shfl_xor(s, 32);
            s += e32;
            float inv = 1.0f / s;
            float sq = 0.0f;
            frag_ab bfr;
            {
                union { unsigned u4[4]; frag_ab f; } cvt;
                #pragma unroll
                for (int k = 0; k < 4; k++) {
                    unsigned lo = f2bf(eb[2 * k] * inv);
                    unsigned hi = f2bf(eb[2 * k + 1] * inv);
                    float fl = bf2f(lo), fh = bf2f(hi);
                    sq += fl * fl + fh * fh;
                    cvt.u4[k] = lo | (hi << 16);
                }
                bfr = cvt.f;
            }
            sq += __shfl_xor(sq, 16);
            sq += __shfl_xor(sq, 32);
            float c32b = bf2f(f2bf(e32 * inv));
            float qj = sq + c32b * c32b;
            int gj = j0 + 16 * n + col;

            f32x4 acc = {0.0f, 0.0f, 0.0f, 0.0f};
            acc = __builtin_amdgcn_mfma_f32_16x16x32_bf16(afr, bfr, acc, 0, 0, 0);

            #pragma unroll
            for (int r = 0; r < 4; r++) {
                float g  = fmaf(c32a[r], c32b, acc[r]);      // + class-32 term
                float d2 = fmaf(-2.0f, g, qi[r] + qj);
                float d  = fast_sqrt(fmaxf(d2, 0.0f));
                ssum += (!dg || gj > gi0 + r) ? d : 0.0f;    // strict upper on diag
            }
        }
    }

    // ---- block reduce + fence-free two-level completion protocol (R8/R9)
    #pragma unroll
    for (int off = 32; off; off >>= 1) ssum += __shfl_xor(ssum, off);
    if (l == 0) red[w] = ssum;
    if (diagA) {
        #pragma unroll
        for (int off = 32; off; off >>= 1) {
            ce += __shfl_xor(ce, off);
            fo += __shfl_xor(fo, off);
            mt += __shfl_xor(mt, off);
        }
        if (l == 0) { redc[w] = ce; redf[w] = fo; redm[w] = mt; }
    }
    __syncthreads();

    if (threadIdx.x == 0) {
        float blockSum = red[0] + red[1] + red[2] + red[3];
        if (diagA) {
            int did = b * NTILES + ti;
            __hip_atomic_store(&part_ce[did], redc[0] + redc[1] + redc[2] + redc[3],
                               __ATOMIC_RELAXED, __HIP_MEMORY_SCOPE_AGENT);
            __hip_atomic_store(&part_fo[did], redf[0] + redf[1] + redf[2] + redf[3],
                               __ATOMIC_RELAXED, __HIP_MEMORY_SCOPE_AGENT);
            __hip_atomic_store(&part_mt[did], redm[0] + redm[1] + redm[2] + redm[3],
                               __ATOMIC_RELAXED, __HIP_MEMORY_SCOPE_AGENT);
        }
        int slot = (bid & (NSLOT - 1)) * SLOTSTR;
        __hip_atomic_fetch_add(&slotf[slot], blockSum,
                               __ATOMIC_RELAXED, __HIP_MEMORY_SCOPE_AGENT);
        asm volatile("s_waitcnt vmcnt(0)" ::: "memory");   // order stores before count
        unsigned o = __hip_atomic_fetch_add(&subcnt[slot], 1u,
                                            __ATOMIC_RELAXED, __HIP_MEMORY_SCOPE_AGENT);
        int last = 0;
        if (o == (PAIRBLK / NSLOT) - 1) {                  // 33rd block of this slot
            unsigned o2 = __hip_atomic_fetch_add(master, 1u,
                                                 __ATOMIC_RELAXED, __HIP_MEMORY_SCOPE_AGENT);
            last = (o2 == NSLOT - 1);
        }
        lastFlag = last;
    }
    __syncthreads();
    if (!lastFlag) return;

    // ---- winner-only finalize (all partials coherent via agent atomics) ----
    double dce = 0.0, dfo = 0.0, dpr = 0.0;
    int dmt = 0;
    for (int i = threadIdx.x; i < NSLOT; i += 256)
        dpr += (double)__hip_atomic_load(&slotf[i * SLOTSTR],
                                         __ATOMIC_RELAXED, __HIP_MEMORY_SCOPE_AGENT);
    for (int i = threadIdx.x; i < NDIAG; i += 256) {
        dce += (double)__hip_atomic_load(&part_ce[i],
                                         __ATOMIC_RELAXED, __HIP_MEMORY_SCOPE_AGENT);
        dfo += (double)__hip_atomic_load(&part_fo[i],
                                         __ATOMIC_RELAXED, __HIP_MEMORY_SCOPE_AGENT);
        dmt += __hip_atomic_load(&part_mt[i],
                                 __ATOMIC_RELAXED, __HIP_MEMORY_SCOPE_AGENT);
    }
    #pragma unroll
    for (int off = 32; off; off >>= 1) {
        dce += __shfl_xor(dce, off);
        dfo += __shfl_xor(dfo, off);
        dpr += __shfl_xor(dpr, off);
        dmt += __shfl_xor(dmt, off);
    }
    if (l == 0) { lds_ce[w] = dce; lds_fo[w] = dfo; lds_pr[w] = dpr; lds_mt[w] = dmt; }
    __syncthreads();
    if (threadIdx.x == 0) {
        double tce = lds_ce[0] + lds_ce[1] + lds_ce[2] + lds_ce[3];
        double tfo = lds_fo[0] + lds_fo[1] + lds_fo[2] + lds_fo[3];
        double tpr = lds_pr[0] + lds_pr[1] + lds_pr[2] + lds_pr[3];
        int    tmt = lds_mt[0] + lds_mt[1] + lds_mt[2] + lds_mt[3];

        double BN = (double)(BB * NN);
        double loss = (tce / BN) * (tfo / BN);
        double dice = 1.0 - 2.0 * ((double)tmt + 1.0) / (2.0 * BN + 1.0);
        double S = 2.0 * tpr;                    // full matrix sum (diag = 0)
        double mean_pred = S / (BN * (double)NN);
        double dml = 0.05 * log(0.05) - 0.05 * mean_pred;
        out[0] = (float)(loss + dice + dml);
    }
}

extern "C" void kernel_launch(void* const* d_in, const int* in_sizes, int n_in,
                              void* d_out, int out_size, void* d_ws, size_t ws_size,
                              hipStream_t stream)
{
    const float* pred        = (const float*)d_in[0];
    // d_in[1] = y_ohe: unused — the double-where provably collapses dis_map to 0.05
    const int*   targets     = (const int*)d_in[2];
    const int*   pred_choice = (const int*)d_in[3];

    char* ws = (char*)d_ws;
    size_t off = 0;
    float* slotf = (float*)ws;                               // 64 slots x 128 B
    off += (size_t)NSLOT * SLOTSTR * sizeof(float);
    unsigned* subcnt = (unsigned*)(ws + off);                // 64 counters x 128 B
    off += (size_t)NSLOT * SLOTSTR * sizeof(unsigned);
    unsigned* master = (unsigned*)(ws + off);
    off += 128;                                              // keep alignment
    size_t zbytes = off;                                     // contiguous zero region
    float* part_ce = (float*)(ws + off);                     // NDIAG f32 (atomic stores)
    off += (size_t)NDIAG * sizeof(float);
    float* part_fo = (float*)(ws + off);
    off += (size_t)NDIAG * sizeof(float);
    int* part_mt = (int*)(ws + off);
    off += (size_t)NDIAG * sizeof(int);

    hipMemsetAsync(ws, 0, zbytes, stream);                   // slots+counts+master
    fused_kernel<<<PAIRBLK, 256, 0, stream>>>(pred, targets, pred_choice,
                                              slotf, subcnt, master,
                                              part_ce, part_fo, part_mt,
                                              (float*)d_out);
}

// Round 13
// 21.212 us; speedup vs baseline: 1.7084x; 1.7084x over previous
//
#include <hip/hip_runtime.h>
#include <math.h>

#define BB 2
#define NN 4096
#define CC 33
#define RP 40                         // bf16 row pitch in ushorts (80 B, 16B-aligned)
#define TILE 64
#define NTILES (NN / TILE)            // 64
#define NPB 1056                      // 64x128 blocks per batch = sum over ti of (32 - ti/2)
#define ROWBLK 256                    // 256 blocks x 32 rows (8 rows/wave, 8 lanes/row)
#define PAIRBLK (BB * NPB)            // 2112 pair blocks = 33 per slot x 64 slots
#define NSLOT 64
#define SLOTSTR 32                    // 32 words = 128 B between slots (distinct L2 lines)

typedef __attribute__((ext_vector_type(8))) short frag_ab;   // 8 bf16 (4 VGPRs)
typedef __attribute__((ext_vector_type(4))) float f32x4;     // 4 fp32 accum

__device__ __forceinline__ float fast_sqrt(float x) {
    return __builtin_amdgcn_sqrtf(x);                        // v_sqrt_f32, ~2 ULP
}
__device__ __forceinline__ unsigned f2bf(float x) {          // RNE, x >= 0 finite
    unsigned u = __float_as_uint(x);
    return (u + 0x7FFFu + ((u >> 16) & 1u)) >> 16;
}
__device__ __forceinline__ float bf2f(unsigned b) {
    return __uint_as_float(b << 16);
}

// ---------------- kernel 1: softmax, 8 rows/wave (8 lanes x 4 classes each;
// class 32 on group leader). Flat float4 staging of 32 rows -> LDS; 3-round
// shfl_xor softmax; packed uint2/uint4 bf16 stores. Block 0 zeroes slots.
__global__ __launch_bounds__(256) void row_kernel(
    const float* __restrict__ pred, const int* __restrict__ targets,
    const int* __restrict__ pred_choice, unsigned short* __restrict__ p16,
    float* __restrict__ sqn, float2* __restrict__ part_row,
    int* __restrict__ part_match, float* __restrict__ slotf,
    unsigned* __restrict__ subcnt, unsigned* __restrict__ master)
{
    __shared__ __align__(16) float sraw[32 * CC];     // 4.2 KB
    __shared__ float2 lds_cf[4];
    __shared__ int lds_mt[4];

    if (blockIdx.x == 0) {
        for (int i = threadIdx.x; i < NSLOT * SLOTSTR; i += 256) {
            slotf[i] = 0.0f;
            subcnt[i] = 0u;
        }
        if (threadIdx.x == 0) *master = 0u;
    }

    {   // flat coalesced staging: 32 rows = 1056 floats = 264 float4 (aligned)
        const float4* src = (const float4*)(pred + (size_t)blockIdx.x * 32 * CC);
        float4* dst = (float4*)sraw;
        for (int k = threadIdx.x; k < 264; k += 256) dst[k] = src[k];
    }
    __syncthreads();

    int l = threadIdx.x & 63;
    int w = threadIdx.x >> 6;
    int r = l >> 3;                    // row within wave (0..7)
    int c = l & 7;                     // class chunk: classes 4c..4c+3
    int rloc = w * 8 + r;              // row within block (0..31)
    int row = blockIdx.x * 32 + rloc;

    float v[4];
    #pragma unroll
    for (int k = 0; k < 4; k++) v[k] = sraw[rloc * CC + 4 * c + k];
    float v32 = sraw[rloc * CC + 32];

    float m = fmaxf(fmaxf(v[0], v[1]), fmaxf(v[2], v[3]));
    if (c == 0) m = fmaxf(m, v32);
    m = fmaxf(m, __shfl_xor(m, 1));
    m = fmaxf(m, __shfl_xor(m, 2));
    m = fmaxf(m, __shfl_xor(m, 4));

    float e[4];
    float s = 0.0f;
    #pragma unroll
    for (int k = 0; k < 4; k++) { e[k] = __expf(v[k] - m); s += e[k]; }
    float e32 = __expf(v32 - m);
    if (c == 0) s += e32;
    s += __shfl_xor(s, 1);
    s += __shfl_xor(s, 2);
    s += __shfl_xor(s, 4);
    float inv = 1.0f / s;

    // pack rounded bf16 probs + sqn in ROUNDED space
    unsigned pb[4];
    float sq = 0.0f;
    #pragma unroll
    for (int k = 0; k < 4; k++) {
        pb[k] = f2bf(e[k] * inv);
        float pf = bf2f(pb[k]);
        sq += pf * pf;
    }
    unsigned c32u = f2bf(e32 * inv);
    float c32 = bf2f(c32u);
    if (c == 0) sq += c32 * c32;
    sq += __shfl_xor(sq, 1);
    sq += __shfl_xor(sq, 2);
    sq += __shfl_xor(sq, 4);

    {   // 8B packed store: classes 4c..4c+3 (byte off = row*80 + 8c, 8B-aligned)
        uint2 st = make_uint2(pb[0] | (pb[1] << 16), pb[2] | (pb[3] << 16));
        *(uint2*)&p16[(size_t)row * RP + 4 * c] = st;
    }
    if (c == 0) {                      // class 32 + zero pad 33..39 (16B-aligned)
        uint4 st = make_uint4(c32u, 0u, 0u, 0u);
        *(uint4*)&p16[(size_t)row * RP + 32] = st;
        sqn[row] = sq;
    }

    // CE / focal / match (raw-space prob of target class)
    int tg = targets[row];
    float cand = 0.0f;
    if (tg < 32) {
        int cc = tg >> 2, kk = tg & 3;
        if (cc == c) cand = e[kk];
    } else if (c == 0) cand = e32;
    cand += __shfl_xor(cand, 1);
    cand += __shfl_xor(cand, 2);
    cand += __shfl_xor(cand, 4);

    float ce = 0.0f, fo = 0.0f; int mt = 0;
    if (c == 0) {
        float pt = cand * inv;
        ce = -__logf(pt);
        float om = 1.0f - pt;
        fo = om * om;
        mt = (tg == pred_choice[row]) ? 1 : 0;
    }
    ce += __shfl_xor(ce, 8);  ce += __shfl_xor(ce, 16);  ce += __shfl_xor(ce, 32);
    fo += __shfl_xor(fo, 8);  fo += __shfl_xor(fo, 16);  fo += __shfl_xor(fo, 32);
    mt += __shfl_xor(mt, 8);  mt += __shfl_xor(mt, 16);  mt += __shfl_xor(mt, 32);

    if (l == 0) { lds_cf[w] = make_float2(ce, fo); lds_mt[w] = mt; }
    __syncthreads();
    if (threadIdx.x == 0) {
        float2 a = lds_cf[0], b2 = lds_cf[1], c2 = lds_cf[2], d = lds_cf[3];
        part_row[blockIdx.x] = make_float2(a.x + b2.x + c2.x + d.x,
                                           a.y + b2.y + c2.y + d.y);
        part_match[blockIdx.x] = lds_mt[0] + lds_mt[1] + lds_mt[2] + lds_mt[3];
    }
}

// ---------------- kernel 2: 64x128 Gram tiles via bf16 MFMA (R9 verbatim,
// closed-form decode). LDS linear 80B pitch staging; fence-free fused
// finalize via 64-slot agent-atomic protocol; winner block finalizes.
__global__ __launch_bounds__(256) void pair_kernel(
    const unsigned short* __restrict__ p16, const float* __restrict__ sqn,
    const float2* __restrict__ part_row, const int* __restrict__ part_match,
    float* __restrict__ slotf, unsigned* __restrict__ subcnt,
    unsigned* __restrict__ master, float* __restrict__ out)
{
    __shared__ __align__(16) unsigned short spi[TILE * RP];
    __shared__ __align__(16) unsigned short spj[2][TILE * RP];
    __shared__ float ssqi[TILE], ssqj[2][TILE];
    __shared__ float red[4];
    __shared__ int lastFlag;
    __shared__ double lds_ce[4], lds_fo[4], lds_pr[4];
    __shared__ int lds_mt[4];

    int bid = blockIdx.x;
    int b = bid / NPB;
    int t = bid % NPB;

    // closed-form decode: row-pair p has (32-p) blocks each for ti=2p,2p+1;
    // cum(p) = p*(65-p)
    int p = (int)(32.5f - fast_sqrt(fmaxf(1056.25f - (float)t, 0.0f)));
    if (p < 0) p = 0;
    if (p > 31) p = 31;
    while (p > 0 && p * (65 - p) > t) --p;
    while (p < 31 && (p + 1) * (64 - p) <= t) ++p;
    int rem = t - p * (65 - p);
    int c0 = 32 - p;
    int ti = 2 * p + (rem >= c0);
    int u = (rem >= c0) ? rem - c0 : rem;
    int tjA = ti + 2 * u;
    bool hasB = (tjA + 1 < NTILES);
    bool diagA = (tjA == ti);

    int i0 = ti * TILE, j0A = tjA * TILE;

    // linear staging: each tile is a contiguous 5120B block of p16
    const float4* srci  = (const float4*)(p16 + ((size_t)b * NN + i0) * RP);
    const float4* srcjA = (const float4*)(p16 + ((size_t)b * NN + j0A) * RP);
    float4* di  = (float4*)spi;
    float4* djA = (float4*)spj[0];
    for (int k = threadIdx.x; k < TILE * (RP / 8); k += 256) {  // 320 float4 each
        di[k]  = srci[k];
        djA[k] = srcjA[k];
    }
    if (hasB) {
        const float4* srcjB = srcjA + TILE * (RP / 8);          // next tile contiguous
        float4* djB = (float4*)spj[1];
        for (int k = threadIdx.x; k < TILE * (RP / 8); k += 256)
            djB[k] = srcjB[k];
    }
    if (threadIdx.x < TILE)
        ssqi[threadIdx.x] = sqn[b * NN + i0 + threadIdx.x];
    else if (threadIdx.x < 2 * TILE)
        ssqj[0][threadIdx.x - TILE] = sqn[b * NN + j0A + (threadIdx.x - TILE)];
    else if (hasB && threadIdx.x < 3 * TILE)
        ssqj[1][threadIdx.x - 2 * TILE] = sqn[b * NN + j0A + TILE + (threadIdx.x - 2 * TILE)];
    __syncthreads();

    int l = threadIdx.x & 63;
    int w = threadIdx.x >> 6;          // wave = 16-row strip of the i-tile
    int col = l & 15;
    int kc = l >> 4;                   // k-chunk 0..3 (8 bf16 each)

    // A fragment: rows 16w..16w+15 of i-tile, k = kc*8..kc*8+7 (reused x8 MFMAs)
    frag_ab afr = *(const frag_ab*)&spi[(16 * w + col) * RP + kc * 8];

    // per-lane row metadata (C layout: col=lane&15, row=(lane>>4)*4+r)
    float qi[4], c32a[4];
    #pragma unroll
    for (int r = 0; r < 4; r++) {
        int ir = 16 * w + kc * 4 + r;
        qi[r]   = ssqi[ir];
        c32a[r] = bf2f(spi[ir * RP + 32]);
    }
    int gi0 = i0 + 16 * w + kc * 4;    // gi = gi0 + r

    float ssum = 0.0f;

    #pragma unroll
    for (int jt = 0; jt < 2; jt++) {
        if (jt == 1 && !hasB) break;                 // block-uniform
        const unsigned short* spjx = spj[jt];
        const float* ssqx = ssqj[jt];
        int j0 = j0A + jt * TILE;
        bool dg = (jt == 0) && diagA;

        #pragma unroll
        for (int n = 0; n < 4; n++) {  // 16-col subtiles of this j-tile
            frag_ab bfr = *(const frag_ab*)&spjx[(16 * n + col) * RP + kc * 8];
            f32x4 acc = {0.0f, 0.0f, 0.0f, 0.0f};
            acc = __builtin_amdgcn_mfma_f32_16x16x32_bf16(afr, bfr, acc, 0, 0, 0);

            float c32b = bf2f(spjx[(16 * n + col) * RP + 32]);
            float qj   = ssqx[16 * n + col];
            int   gj   = j0 + 16 * n + col;

            #pragma unroll
            for (int r = 0; r < 4; r++) {
                float g  = fmaf(c32a[r], c32b, acc[r]);      // + class-32 term
                float d2 = fmaf(-2.0f, g, qi[r] + qj);
                float d  = fast_sqrt(fmaxf(d2, 0.0f));
                ssum += (!dg || gj > gi0 + r) ? d : 0.0f;    // strict upper on diag
            }
        }
    }

    #pragma unroll
    for (int off = 32; off; off >>= 1) ssum += __shfl_xor(ssum, off);
    if (l == 0) red[w] = ssum;
    __syncthreads();

    if (threadIdx.x == 0) {
        float blockSum = red[0] + red[1] + red[2] + red[3];
        int slot = (bid & (NSLOT - 1)) * SLOTSTR;
        __hip_atomic_fetch_add(&slotf[slot], blockSum,
                               __ATOMIC_RELAXED, __HIP_MEMORY_SCOPE_AGENT);
        asm volatile("s_waitcnt vmcnt(0)" ::: "memory");   // order fadd before count
        unsigned o = __hip_atomic_fetch_add(&subcnt[slot], 1u,
                                            __ATOMIC_RELAXED, __HIP_MEMORY_SCOPE_AGENT);
        int last = 0;
        if (o == (PAIRBLK / NSLOT) - 1) {                  // 33rd block of this slot
            unsigned o2 = __hip_atomic_fetch_add(master, 1u,
                                                 __ATOMIC_RELAXED, __HIP_MEMORY_SCOPE_AGENT);
            last = (o2 == NSLOT - 1);
        }
        lastFlag = last;
    }
    __syncthreads();
    if (!lastFlag) return;

    // ---- fused finalize (winner block only; slots coherent via agent atomics,
    //      part_* via kernel-boundary) ----
    double ce = 0.0, fo = 0.0, pr = 0.0;
    int mt = 0;
    for (int i = threadIdx.x; i < ROWBLK; i += 256) {
        float2 v = part_row[i];
        ce += (double)v.x;
        fo += (double)v.y;
        mt += part_match[i];
    }
    for (int i = threadIdx.x; i < NSLOT; i += 256)
        pr += (double)__hip_atomic_load(&slotf[i * SLOTSTR],
                                        __ATOMIC_RELAXED, __HIP_MEMORY_SCOPE_AGENT);

    #pragma unroll
    for (int off = 32; off; off >>= 1) {
        ce += __shfl_xor(ce, off);
        fo += __shfl_xor(fo, off);
        pr += __shfl_xor(pr, off);
        mt += __shfl_xor(mt, off);
    }
    if (l == 0) { lds_ce[w] = ce; lds_fo[w] = fo; lds_pr[w] = pr; lds_mt[w] = mt; }
    __syncthreads();
    if (threadIdx.x == 0) {
        double tce = lds_ce[0] + lds_ce[1] + lds_ce[2] + lds_ce[3];
        double tfo = lds_fo[0] + lds_fo[1] + lds_fo[2] + lds_fo[3];
        double tpr = lds_pr[0] + lds_pr[1] + lds_pr[2] + lds_pr[3];
        int    tmt = lds_mt[0] + lds_mt[1] + lds_mt[2] + lds_mt[3];

        double BN = (double)(BB * NN);
        double loss = (tce / BN) * (tfo / BN);
        double dice = 1.0 - 2.0 * ((double)tmt + 1.0) / (2.0 * BN + 1.0);
        double S = 2.0 * tpr;                    // full matrix sum (diag = 0)
        double mean_pred = S / (BN * (double)NN);
        double dml = 0.05 * log(0.05) - 0.05 * mean_pred;
        out[0] = (float)(loss + dice + dml);
    }
}

extern "C" void kernel_launch(void* const* d_in, const int* in_sizes, int n_in,
                              void* d_out, int out_size, void* d_ws, size_t ws_size,
                              hipStream_t stream)
{
    const float* pred        = (const float*)d_in[0];
    // d_in[1] = y_ohe: unused — the double-where provably collapses dis_map to 0.05
    const int*   targets     = (const int*)d_in[2];
    const int*   pred_choice = (const int*)d_in[3];

    char* ws = (char*)d_ws;
    size_t off = 0;
    unsigned short* p16 = (unsigned short*)ws;               // BB*NN*RP ushorts
    off += (size_t)BB * NN * RP * sizeof(unsigned short);
    float* sqn = (float*)(ws + off);
    off += (size_t)BB * NN * sizeof(float);
    off = (off + 127) & ~(size_t)127;
    float2* part_row = (float2*)(ws + off);                  // ROWBLK float2
    off += (size_t)ROWBLK * sizeof(float2);
    int* part_match = (int*)(ws + off);                      // ROWBLK int
    off += (size_t)ROWBLK * sizeof(int);
    off = (off + 127) & ~(size_t)127;
    float* slotf = (float*)(ws + off);                       // 64 slots x 128 B
    off += (size_t)NSLOT * SLOTSTR * sizeof(float);
    unsigned* subcnt = (unsigned*)(ws + off);                // 64 counters x 128 B
    off += (size_t)NSLOT * SLOTSTR * sizeof(unsigned);
    unsigned* master = (unsigned*)(ws + off);
    off += sizeof(unsigned);

    row_kernel<<<ROWBLK, 256, 0, stream>>>(pred, targets, pred_choice,
                                           p16, sqn, part_row, part_match,
                                           slotf, subcnt, master);
    pair_kernel<<<PAIRBLK, 256, 0, stream>>>(p16, sqn, part_row, part_match,
                                             slotf, subcnt, master, (float*)d_out);
}

// Round 14
// 20.128 us; speedup vs baseline: 1.8004x; 1.0538x over previous
//
#include <hip/hip_runtime.h>
#include <math.h>

#define BB 2
#define NN 4096
#define CC 33
#define RP 40                         // bf16 row pitch in ushorts (80 B): probs 0..32,
                                      // pad 33, sqn f32 in 34..35, pad 36..39
#define TILE 64
#define NTILES (NN / TILE)            // 64
#define NPB 715                       // 64x192 blocks per batch = sum ceil((64-ti)/3)
#define ROWBLK 256                    // 256 blocks x 32 rows (8 rows/wave, 8 lanes/row)
#define PAIRBLK (BB * NPB)            // 1430 pair blocks
#define NSLOT 64
#define SLOTSTR 32                    // 128 B between slots (distinct L2 lines)

typedef __attribute__((ext_vector_type(8))) short frag_ab;   // 8 bf16 (4 VGPRs)
typedef __attribute__((ext_vector_type(4))) float f32x4;     // 4 fp32 accum

__device__ __forceinline__ float fast_sqrt(float x) {
    return __builtin_amdgcn_sqrtf(x);                        // v_sqrt_f32, ~2 ULP
}
__device__ __forceinline__ unsigned f2bf(float x) {          // RNE, x >= 0 finite
    unsigned u = __float_as_uint(x);
    return (u + 0x7FFFu + ((u >> 16) & 1u)) >> 16;
}
__device__ __forceinline__ float bf2f(unsigned b) {
    return __uint_as_float(b << 16);
}

// ---------------- kernel 1: softmax, 8 rows/wave (8 lanes x 4 classes each;
// class 32 on group leader). sqn packed into row pad (ushorts 34..35).
__global__ __launch_bounds__(256) void row_kernel(
    const float* __restrict__ pred, const int* __restrict__ targets,
    const int* __restrict__ pred_choice, unsigned short* __restrict__ p16,
    float2* __restrict__ part_row, int* __restrict__ part_match,
    float* __restrict__ slotf, unsigned* __restrict__ subcnt,
    unsigned* __restrict__ master)
{
    __shared__ __align__(16) float sraw[32 * CC];     // 4.2 KB
    __shared__ float2 lds_cf[4];
    __shared__ int lds_mt[4];

    if (blockIdx.x == 0) {
        for (int i = threadIdx.x; i < NSLOT * SLOTSTR; i += 256) {
            slotf[i] = 0.0f;
            subcnt[i] = 0u;
        }
        if (threadIdx.x == 0) *master = 0u;
    }

    {   // flat coalesced staging: 32 rows = 1056 floats = 264 float4 (aligned)
        const float4* src = (const float4*)(pred + (size_t)blockIdx.x * 32 * CC);
        float4* dst = (float4*)sraw;
        for (int k = threadIdx.x; k < 264; k += 256) dst[k] = src[k];
    }
    __syncthreads();

    int l = threadIdx.x & 63;
    int w = threadIdx.x >> 6;
    int r = l >> 3;                    // row within wave (0..7)
    int c = l & 7;                     // class chunk: classes 4c..4c+3
    int rloc = w * 8 + r;              // row within block (0..31)
    int row = blockIdx.x * 32 + rloc;

    float v[4];
    #pragma unroll
    for (int k = 0; k < 4; k++) v[k] = sraw[rloc * CC + 4 * c + k];
    float v32 = sraw[rloc * CC + 32];

    float m = fmaxf(fmaxf(v[0], v[1]), fmaxf(v[2], v[3]));
    if (c == 0) m = fmaxf(m, v32);
    m = fmaxf(m, __shfl_xor(m, 1));
    m = fmaxf(m, __shfl_xor(m, 2));
    m = fmaxf(m, __shfl_xor(m, 4));

    float e[4];
    float s = 0.0f;
    #pragma unroll
    for (int k = 0; k < 4; k++) { e[k] = __expf(v[k] - m); s += e[k]; }
    float e32 = __expf(v32 - m);
    if (c == 0) s += e32;
    s += __shfl_xor(s, 1);
    s += __shfl_xor(s, 2);
    s += __shfl_xor(s, 4);
    float inv = 1.0f / s;

    // pack rounded bf16 probs + sqn in ROUNDED space
    unsigned pb[4];
    float sq = 0.0f;
    #pragma unroll
    for (int k = 0; k < 4; k++) {
        pb[k] = f2bf(e[k] * inv);
        float pf = bf2f(pb[k]);
        sq += pf * pf;
    }
    unsigned c32u = f2bf(e32 * inv);
    float c32 = bf2f(c32u);
    if (c == 0) sq += c32 * c32;
    sq += __shfl_xor(sq, 1);
    sq += __shfl_xor(sq, 2);
    sq += __shfl_xor(sq, 4);

    {   // 8B packed store: classes 4c..4c+3
        uint2 st = make_uint2(pb[0] | (pb[1] << 16), pb[2] | (pb[3] << 16));
        *(uint2*)&p16[(size_t)row * RP + 4 * c] = st;
    }
    if (c == 0) {                      // ushorts 32..39: c32, 0, sq(f32), 0, 0
        uint4 st = make_uint4(c32u, __float_as_uint(sq), 0u, 0u);
        *(uint4*)&p16[(size_t)row * RP + 32] = st;
    }

    // CE / focal / match (raw-space prob of target class)
    int tg = targets[row];
    float cand = 0.0f;
    if (tg < 32) {
        int cc = tg >> 2, kk = tg & 3;
        if (cc == c) cand = e[kk];
    } else if (c == 0) cand = e32;
    cand += __shfl_xor(cand, 1);
    cand += __shfl_xor(cand, 2);
    cand += __shfl_xor(cand, 4);

    float ce = 0.0f, fo = 0.0f; int mt = 0;
    if (c == 0) {
        float pt = cand * inv;
        ce = -__logf(pt);
        float om = 1.0f - pt;
        fo = om * om;
        mt = (tg == pred_choice[row]) ? 1 : 0;
    }
    ce += __shfl_xor(ce, 8);  ce += __shfl_xor(ce, 16);  ce += __shfl_xor(ce, 32);
    fo += __shfl_xor(fo, 8);  fo += __shfl_xor(fo, 16);  fo += __shfl_xor(fo, 32);
    mt += __shfl_xor(mt, 8);  mt += __shfl_xor(mt, 16);  mt += __shfl_xor(mt, 32);

    if (l == 0) { lds_cf[w] = make_float2(ce, fo); lds_mt[w] = mt; }
    __syncthreads();
    if (threadIdx.x == 0) {
        float2 a = lds_cf[0], b2 = lds_cf[1], c2 = lds_cf[2], d = lds_cf[3];
        part_row[blockIdx.x] = make_float2(a.x + b2.x + c2.x + d.x,
                                           a.y + b2.y + c2.y + d.y);
        part_match[blockIdx.x] = lds_mt[0] + lds_mt[1] + lds_mt[2] + lds_mt[3];
    }
}

// ---------------- kernel 2: 64x192 Gram tiles via bf16 MFMA. One i-tile x
// up to 3 j-tiles per block (A-frag reused x12 MFMAs). sqn read from the row
// pad - no side staging. Fence-free 64-slot completion protocol (uneven slot
// counts 22/23); winner block finalizes.
__global__ __launch_bounds__(256) void pair_kernel(
    const unsigned short* __restrict__ p16,
    const float2* __restrict__ part_row, const int* __restrict__ part_match,
    float* __restrict__ slotf, unsigned* __restrict__ subcnt,
    unsigned* __restrict__ master, float* __restrict__ out)
{
    __shared__ __align__(16) unsigned short spi[TILE * RP];
    __shared__ __align__(16) unsigned short spj[3 * TILE * RP];
    __shared__ float red[4];
    __shared__ int lastFlag;
    __shared__ double lds_ce[4], lds_fo[4], lds_pr[4];
    __shared__ int lds_mt[4];

    int bid = blockIdx.x;
    int b = bid / NPB;
    int t = bid % NPB;

    // decode: row ti has ceil((64-ti)/3) blocks (block-uniform scalar loop)
    int ti = 0, rem = t;
    while (rem >= (NTILES - ti + 2) / 3) { rem -= (NTILES - ti + 2) / 3; ++ti; }
    int tjA = ti + 3 * rem;
    int avail = NTILES - tjA; if (avail > 3) avail = 3;
    bool diagA = (tjA == ti);
    int i0 = ti * TILE, j0A = tjA * TILE;

    // linear staging: i-tile + avail j-tiles, all contiguous 5120B chunks
    {
        const float4* srci = (const float4*)(p16 + ((size_t)b * NN + i0) * RP);
        const float4* srcj = (const float4*)(p16 + ((size_t)b * NN + j0A) * RP);
        float4* di = (float4*)spi;
        float4* dj = (float4*)spj;
        int jf4 = avail * 320;
        for (int k = threadIdx.x; k < 320; k += 256) di[k] = srci[k];
        for (int k = threadIdx.x; k < jf4; k += 256) dj[k] = srcj[k];
    }
    __syncthreads();

    int l = threadIdx.x & 63;
    int w = threadIdx.x >> 6;          // wave = 16-row strip of the i-tile
    int col = l & 15;
    int kc = l >> 4;                   // k-chunk 0..3 (8 bf16 each)

    // A fragment: rows 16w..16w+15 of i-tile, k = kc*8..kc*8+7 (reused x12)
    frag_ab afr = *(const frag_ab*)&spi[(16 * w + col) * RP + kc * 8];

    // per-lane row metadata from the row pad (C layout rows 16w+kc*4+r)
    float qi[4], c32a[4];
    #pragma unroll
    for (int r = 0; r < 4; r++) {
        int ir = 16 * w + kc * 4 + r;
        qi[r]   = __uint_as_float(*(const unsigned*)&spi[ir * RP + 34]);
        c32a[r] = bf2f(spi[ir * RP + 32]);
    }
    int gi0 = i0 + 16 * w + kc * 4;    // gi = gi0 + r

    float ssum = 0.0f;

    #pragma unroll
    for (int jt = 0; jt < 3; jt++) {
        if (jt >= avail) break;                      // block-uniform
        const unsigned short* spjx = spj + jt * TILE * RP;
        int j0 = j0A + jt * TILE;
        bool dg = (jt == 0) && diagA;

        #pragma unroll
        for (int n = 0; n < 4; n++) {  // 16-col subtiles of this j-tile
            int jr = 16 * n + col;
            frag_ab bfr = *(const frag_ab*)&spjx[jr * RP + kc * 8];
            f32x4 acc = {0.0f, 0.0f, 0.0f, 0.0f};
            acc = __builtin_amdgcn_mfma_f32_16x16x32_bf16(afr, bfr, acc, 0, 0, 0);

            float c32b = bf2f(spjx[jr * RP + 32]);
            float qj   = __uint_as_float(*(const unsigned*)&spjx[jr * RP + 34]);
            int   gj   = j0 + jr - col + col;        // = j0 + 16n + col

            #pragma unroll
            for (int r = 0; r < 4; r++) {
                float g  = fmaf(c32a[r], c32b, acc[r]);      // + class-32 term
                float d2 = fmaf(-2.0f, g, qi[r] + qj);
                float d  = fast_sqrt(fmaxf(d2, 0.0f));
                ssum += (!dg || gj > gi0 + r) ? d : 0.0f;    // strict upper on diag
            }
        }
    }

    #pragma unroll
    for (int off = 32; off; off >>= 1) ssum += __shfl_xor(ssum, off);
    if (l == 0) red[w] = ssum;
    __syncthreads();

    if (threadIdx.x == 0) {
        float blockSum = red[0] + red[1] + red[2] + red[3];
        int slotIdx = bid & (NSLOT - 1);
        int slot = slotIdx * SLOTSTR;
        unsigned expect = (unsigned)(PAIRBLK / NSLOT) + (slotIdx < (PAIRBLK % NSLOT) ? 1u : 0u);
        __hip_atomic_fetch_add(&slotf[slot], blockSum,
                               __ATOMIC_RELAXED, __HIP_MEMORY_SCOPE_AGENT);
        asm volatile("s_waitcnt vmcnt(0)" ::: "memory");   // order fadd before count
        unsigned o = __hip_atomic_fetch_add(&subcnt[slot], 1u,
                                            __ATOMIC_RELAXED, __HIP_MEMORY_SCOPE_AGENT);
        int last = 0;
        if (o == expect - 1) {                             // last block of this slot
            unsigned o2 = __hip_atomic_fetch_add(master, 1u,
                                                 __ATOMIC_RELAXED, __HIP_MEMORY_SCOPE_AGENT);
            last = (o2 == NSLOT - 1);
        }
        lastFlag = last;
    }
    __syncthreads();
    if (!lastFlag) return;

    // ---- fused finalize (winner block only; slots coherent via agent atomics,
    //      part_* via kernel-boundary) ----
    double ce = 0.0, fo = 0.0, pr = 0.0;
    int mt = 0;
    for (int i = threadIdx.x; i < ROWBLK; i += 256) {
        float2 v = part_row[i];
        ce += (double)v.x;
        fo += (double)v.y;
        mt += part_match[i];
    }
    for (int i = threadIdx.x; i < NSLOT; i += 256)
        pr += (double)__hip_atomic_load(&slotf[i * SLOTSTR],
                                        __ATOMIC_RELAXED, __HIP_MEMORY_SCOPE_AGENT);

    #pragma unroll
    for (int off = 32; off; off >>= 1) {
        ce += __shfl_xor(ce, off);
        fo += __shfl_xor(fo, off);
        pr += __shfl_xor(pr, off);
        mt += __shfl_xor(mt, off);
    }
    if (l == 0) { lds_ce[w] = ce; lds_fo[w] = fo; lds_pr[w] = pr; lds_mt[w] = mt; }
    __syncthreads();
    if (threadIdx.x == 0) {
        double tce = lds_ce[0] + lds_ce[1] + lds_ce[2] + lds_ce[3];
        double tfo = lds_fo[0] + lds_fo[1] + lds_fo[2] + lds_fo[3];
        double tpr = lds_pr[0] + lds_pr[1] + lds_pr[2] + lds_pr[3];
        int    tmt = lds_mt[0] + lds_mt[1] + lds_mt[2] + lds_mt[3];

        double BN = (double)(BB * NN);
        double loss = (tce / BN) * (tfo / BN);
        double dice = 1.0 - 2.0 * ((double)tmt + 1.0) / (2.0 * BN + 1.0);
        double S = 2.0 * tpr;                    // full matrix sum (diag = 0)
        double mean_pred = S / (BN * (double)NN);
        double dml = 0.05 * log(0.05) - 0.05 * mean_pred;
        out[0] = (float)(loss + dice + dml);
    }
}

extern "C" void kernel_launch(void* const* d_in, const int* in_sizes, int n_in,
                              void* d_out, int out_size, void* d_ws, size_t ws_size,
                              hipStream_t stream)
{
    const float* pred        = (const float*)d_in[0];
    // d_in[1] = y_ohe: unused — the double-where provably collapses dis_map to 0.05
    const int*   targets     = (const int*)d_in[2];
    const int*   pred_choice = (const int*)d_in[3];

    char* ws = (char*)d_ws;
    size_t off = 0;
    unsigned short* p16 = (unsigned short*)ws;               // BB*NN*RP ushorts
    off += (size_t)BB * NN * RP * sizeof(unsigned short);
    off = (off + 127) & ~(size_t)127;
    float2* part_row = (float2*)(ws + off);                  // ROWBLK float2
    off += (size_t)ROWBLK * sizeof(float2);
    int* part_match = (int*)(ws + off);                      // ROWBLK int
    off += (size_t)ROWBLK * sizeof(int);
    off = (off + 127) & ~(size_t)127;
    float* slotf = (float*)(ws + off);                       // 64 slots x 128 B
    off += (size_t)NSLOT * SLOTSTR * sizeof(float);
    unsigned* subcnt = (unsigned*)(ws + off);                // 64 counters x 128 B
    off += (size_t)NSLOT * SLOTSTR * sizeof(unsigned);
    unsigned* master = (unsigned*)(ws + off);
    off += sizeof(unsigned);

    row_kernel<<<ROWBLK, 256, 0, stream>>>(pred, targets, pred_choice,
                                           p16, part_row, part_match,
                                           slotf, subcnt, master);
    pair_kernel<<<PAIRBLK, 256, 0, stream>>>(p16, part_row, part_match,
                                             slotf, subcnt, master, (float*)d_out);
}